// Round 6
// baseline (225.850 us; speedup 1.0000x reference)
//
#include <hip/hip_runtime.h>
#include <cstdint>
#include <cstddef>

// T=2048 B=2 E=1024 H=16 hd=64. M = T*B = 4096 rows.
// QSCALE = head_dim^-0.5 * log2(e), folded into wq + bq so softmax runs base-2.
#define QSCALE 0.18033688011112042f

typedef __attribute__((ext_vector_type(8))) short bf16x8;
typedef __attribute__((ext_vector_type(4))) float f32x4;

#define MFMA(a, b, c) __builtin_amdgcn_mfma_f32_16x16x32_bf16(a, b, c, 0, 0, 0)

// boundary sync (attn): drain this wave's DMA (issued >=1 compute-phase ago), barrier.
#define PIPE_SYNC() do {                                   \
    asm volatile("s_waitcnt vmcnt(0)" ::: "memory");       \
    __builtin_amdgcn_sched_barrier(0);                     \
    __builtin_amdgcn_s_barrier();                          \
    __builtin_amdgcn_sched_barrier(0);                     \
  } while (0)

typedef union { unsigned int u[4]; bf16x8 b; } pku;

__device__ __forceinline__ unsigned short cvt_bf16(float x) {
  union { float f; unsigned int u; } v;
  v.f = x;
  unsigned int r = v.u + 0x7FFFu + ((v.u >> 16) & 1u);  // RNE
  return (unsigned short)(r >> 16);
}

__device__ __forceinline__ void gll16(const void* g, void* l) {
  __builtin_amdgcn_global_load_lds(
      (const __attribute__((address_space(1))) unsigned int*)g,
      (__attribute__((address_space(3))) unsigned int*)l, 16, 0, 0);
}

__device__ __forceinline__ float fast_exp2(float x) {
#if __has_builtin(__builtin_amdgcn_exp2f)
  return __builtin_amdgcn_exp2f(x);
#else
  float r; asm("v_exp_f32 %0, %1" : "=v"(r) : "v"(x)); return r;
#endif
}

// pack two fp32 -> two bf16 (lo in low half) in one v_perm_b32
__device__ __forceinline__ unsigned int pack_bf16(float lo, float hi) {
  union { float f; unsigned int u; } a, b;
  a.f = lo; b.f = hi;
  return __builtin_amdgcn_perm(b.u + 0x8000u, a.u + 0x8000u, 0x07060302u);
}

// convert 8 fp32 (two float4) -> uint4 of 8 bf16, with uniform scale
__device__ __forceinline__ uint4 cvt8(float4 a, float4 b, float sc) {
  uint4 o;
  o.x = pack_bf16(a.x * sc, a.y * sc);
  o.y = pack_bf16(a.z * sc, a.w * sc);
  o.z = pack_bf16(b.x * sc, b.y * sc);
  o.w = pack_bf16(b.z * sc, b.w * sc);
  return o;
}

// ---------------- QKV projection GEMM (fp32 in, cvt fused) ----------------
// R0 structure restored: 128x128 tile, BK=64, single 32 KB LDS buffer, two
// __syncthreads per K-step, 3 blocks/CU (best measured: 48.6 us).
// THIS ROUND: cvt_all is DELETED — A (q/k/v) and B (ipw) are read as fp32 and
// converted to bf16 during reg-staging (float4 x2 -> pack_bf16 -> swizzled
// ds_write_b128). Saves ~100 MB of convert-kernel round-trip traffic.
__global__ __launch_bounds__(256, 3) void gemm_qkv(
    const float* __restrict__ Qf,   // [4096][1024] fp32 (query, row = t*2+b)
    const float* __restrict__ Kf,   // key
    const float* __restrict__ Vf,   // value
    const float* __restrict__ Wf,   // [3072][1024] fp32 in_proj_weight
    const float* __restrict__ bias, // [3072] fp32
    unsigned short* __restrict__ Qh,  // [32][2048][64]
    unsigned short* __restrict__ Kh,  // [32][2048][64]
    unsigned short* __restrict__ Vt)  // [32][64][2048] key-permuted
{
  __shared__ unsigned short As[128 * 64];   // 16 KB
  __shared__ unsigned short Bs[128 * 64];   // 16 KB
  const int tid = threadIdx.x;
  const int wave = tid >> 6, lane = tid & 63;
  const int quad = lane >> 4, l16 = lane & 15;
  const int flat = blockIdx.x + (blockIdx.y << 3) + (blockIdx.z << 8);
  const int nf = (flat & 7) * 96 + (flat >> 3);
  const int z = nf >> 8;
  const int m0 = ((nf >> 3) & 31) * 128;
  const int n0 = (nf & 7) * 128;
  const float* Ab = (z == 0 ? Qf : (z == 1 ? Kf : Vf)) + (size_t)m0 * 1024;
  const float* Bb = Wf + ((size_t)z * 1024 + n0) * 1024;
  const float wsc = (z == 0) ? QSCALE : 1.0f;   // fold q-scaling into wq
  const int wr = (wave >> 1) * 64, wc = (wave & 1) * 64;

  const f32x4 z4 = {0.f, 0.f, 0.f, 0.f};
  f32x4 acc[4][4];
#pragma unroll
  for (int i = 0; i < 4; ++i)
#pragma unroll
    for (int j = 0; j < 4; ++j) acc[i][j] = z4;

  for (int k0 = 0; k0 < 1024; k0 += 64) {
    __syncthreads();
#pragma unroll
    for (int j = 0; j < 4; ++j) {
      const int c = j * 256 + tid;          // chunk 0..1023
      const int row = c >> 3, pc = c & 7;   // 8x 8-elem chunks per 64-col row
      const int swz = (pc ^ (row & 7)) * 8; // XOR swizzle on the LDS write
      const float* sa = Ab + (size_t)row * 1024 + k0 + pc * 8;
      const float4 a0 = *(const float4*)sa;
      const float4 a1 = *(const float4*)(sa + 4);
      *(uint4*)&As[row * 64 + swz] = cvt8(a0, a1, 1.0f);
      const float* sb = Bb + (size_t)row * 1024 + k0 + pc * 8;
      const float4 b0 = *(const float4*)sb;
      const float4 b1 = *(const float4*)(sb + 4);
      *(uint4*)&Bs[row * 64 + swz] = cvt8(b0, b1, wsc);
    }
    __syncthreads();   // drains vmcnt+lgkmcnt; staged tile visible
#pragma unroll
    for (int kk = 0; kk < 2; ++kk) {
      bf16x8 af[4], bfr[4];
#pragma unroll
      for (int rt = 0; rt < 4; ++rt) {
        const int row = wr + rt * 16 + l16;
        af[rt] = *(const bf16x8*)&As[row * 64 + ((kk * 4 + quad) ^ (row & 7)) * 8];
      }
#pragma unroll
      for (int ct = 0; ct < 4; ++ct) {
        const int row = wc + ct * 16 + l16;
        bfr[ct] = *(const bf16x8*)&Bs[row * 64 + ((kk * 4 + quad) ^ (row & 7)) * 8];
      }
#pragma unroll
      for (int rt = 0; rt < 4; ++rt)
#pragma unroll
        for (int ct = 0; ct < 4; ++ct)
          acc[rt][ct] = MFMA(af[rt], bfr[ct], acc[rt][ct]);
    }
  }

#pragma unroll
  for (int rt = 0; rt < 4; ++rt)
#pragma unroll
    for (int ct = 0; ct < 4; ++ct) {
      const int gn = n0 + wc + ct * 16 + l16;
      float bv = bias[z * 1024 + gn];
      if (z == 0) bv *= QSCALE;
      const int h = gn >> 6, d = gn & 63;
#pragma unroll
      for (int r = 0; r < 4; ++r) {
        const int gm = m0 + wr + rt * 16 + quad * 4 + r;  // m = t*2 + b
        const int t = gm >> 1, b = gm & 1;
        const int bh = b * 16 + h;
        const unsigned short o = cvt_bf16(acc[rt][ct][r] + bv);
        if (z == 0)      Qh[((size_t)bh * 2048 + t) * 64 + d] = o;
        else if (z == 1) Kh[((size_t)bh * 2048 + t) * 64 + d] = o;
        else {
          const int w32 = t & 31;   // pi: {16hi+4q+r} -> q*8 + hi*4 + r
          const int tp = (t & ~31) | (((w32 >> 2) & 3) << 3) | ((w32 >> 4) << 2) | (w32 & 3);
          Vt[((size_t)bh * 64 + d) * 2048 + tp] = o;
        }
      }
    }
}

// ---------------- flash attention ----------------
// R5-passing version, unchanged: QBLK=128, 512 blocks = 2/CU, W-B-I-C dbuf,
// setprio around the PV MFMA cluster.
__global__ __launch_bounds__(256, 2) void attn(
    const unsigned short* __restrict__ Qh,
    const unsigned short* __restrict__ Kh,
    const unsigned short* __restrict__ Vt,
    unsigned short* __restrict__ O)   // [4096][1024] bf16 (row = t*2+b)
{
  __shared__ unsigned short KV[2][16384];  // 64 KB: per buf Ks [128][64] | Vs [64][128]
  __shared__ float Ls[128];                // pair-combine l partials
  const int tid = threadIdx.x;
  const int wave = tid >> 6, lane = tid & 63;
  const int quad = lane >> 4, l16 = lane & 15;
  const int pair = wave >> 1, kh = wave & 1;
  const int flat = blockIdx.x + (blockIdx.y << 4);   // grid (16,32)
  const int nf = (flat & 7) * 64 + (flat >> 3);      // XCD j: 4 whole bh's
  const int qt = nf & 15, bh = nf >> 4;
  const unsigned short* Qb = Qh + ((size_t)bh * 2048 + qt * 128 + pair * 64) * 64;
  const unsigned short* Kb = Kh + (size_t)bh * 2048 * 64;
  const unsigned short* Vb = Vt + (size_t)bh * 64 * 2048;

  bf16x8 qf[4][2];  // B-frags for S^T = K.Q^T; 4 q-groups of 16 rows
#pragma unroll
  for (int g = 0; g < 4; ++g)
#pragma unroll
    for (int kk = 0; kk < 2; ++kk)
      qf[g][kk] = *(const bf16x8*)(Qb + (size_t)(g * 16 + l16) * 64 + kk * 32 + quad * 8);

  const unsigned short* kp[4];
  const unsigned short* vp[4];
  int klo[4], vlo[4];
#pragma unroll
  for (int j = 0; j < 4; ++j) {
    const int c = wave * 256 + j * 64 + lane;   // chunk 0..1023
    const int r = c >> 3, cc = c & 7;
    kp[j] = Kb + (size_t)r * 64 + (cc ^ (r & 7)) * 8;
    klo[j] = c * 8;
    const int r2 = c >> 4, cc2 = c & 15;
    vp[j] = Vb + (size_t)r2 * 2048 + (cc2 ^ (r2 & 15)) * 8;
    vlo[j] = 8192 + c * 8;
  }

  pku ones;
  ones.u[0] = ones.u[1] = ones.u[2] = ones.u[3] = 0x3F803F80u;  // bf16 1.0 x8

  const f32x4 z4 = {0.f, 0.f, 0.f, 0.f};
  f32x4 oacc[4][4];
  f32x4 lacc[4] = {z4, z4, z4, z4};
#pragma unroll
  for (int g = 0; g < 4; ++g)
#pragma unroll
    for (int c = 0; c < 4; ++c) oacc[g][c] = z4;

#pragma unroll
  for (int j = 0; j < 4; ++j) {
    gll16(kp[j], &KV[0][klo[j]]);
    gll16(vp[j], &KV[0][vlo[j]]);
    kp[j] += 128 * 64;
    vp[j] += 128;
  }

#pragma unroll 1
  for (int it = 0; it < 16; ++it) {
    const int cur = it & 1;
    PIPE_SYNC();         // T(it) landed everywhere; buf[cur^1] free
    if (it < 15) {
#pragma unroll
      for (int j = 0; j < 4; ++j) {
        gll16(kp[j], &KV[cur ^ 1][klo[j]]);
        gll16(vp[j], &KV[cur ^ 1][vlo[j]]);
        kp[j] += 128 * 64;
        vp[j] += 128;
      }
    }
    const unsigned short* Ks = KV[cur];
    const unsigned short* Vs = KV[cur] + 8192;

#pragma unroll
    for (int jj = 0; jj < 2; ++jj) {
      unsigned int pk0[4][2], pk1[4][2];
#pragma unroll
      for (int half = 0; half < 2; ++half) {
        const int ct = jj * 2 + half;
        const int R = kh * 64 + ct * 16 + l16;
        bf16x8 kfr[2];
#pragma unroll
        for (int kk = 0; kk < 2; ++kk)
          kfr[kk] = *(const bf16x8*)&Ks[R * 64 + ((kk * 4 + quad) ^ (R & 7)) * 8];
#pragma unroll
        for (int g = 0; g < 4; ++g) {
          f32x4 sv = z4;
          sv = MFMA(kfr[0], qf[g][0], sv);
          sv = MFMA(kfr[1], qf[g][1], sv);
          f32x4 p;
#pragma unroll
          for (int r = 0; r < 4; ++r) p[r] = fast_exp2(sv[r]);
          pk0[g][half] = pack_bf16(p[0], p[1]);
          pk1[g][half] = pack_bf16(p[2], p[3]);
        }
      }
      const int jjg = kh * 2 + jj;
      __builtin_amdgcn_s_setprio(1);
#pragma unroll
      for (int ctd = 0; ctd < 4; ++ctd) {
        const int R = ctd * 16 + l16;
        const int phys = (jjg * 4 + quad) ^ (R & 15);
        const bf16x8 vv = *(const bf16x8*)&Vs[R * 128 + phys * 8];
#pragma unroll
        for (int g = 0; g < 4; ++g) {
          pku a;
          a.u[0] = pk0[g][0]; a.u[1] = pk1[g][0];
          a.u[2] = pk0[g][1]; a.u[3] = pk1[g][1];
          oacc[g][ctd] = MFMA(a.b, vv, oacc[g][ctd]);
        }
      }
#pragma unroll
      for (int g = 0; g < 4; ++g) {
        pku a;
        a.u[0] = pk0[g][0]; a.u[1] = pk1[g][0];
        a.u[2] = pk0[g][1]; a.u[3] = pk1[g][1];
        lacc[g] = MFMA(a.b, ones.b, lacc[g]);
      }
      __builtin_amdgcn_s_setprio(0);
    }
  }

  __syncthreads();
  float* Fp = (float*)KV;               // pair region: pair*4096 floats [q][d]
  if (kh == 1) {
#pragma unroll
    for (int g = 0; g < 4; ++g) {
#pragma unroll
      for (int ctd = 0; ctd < 4; ++ctd)
#pragma unroll
        for (int r = 0; r < 4; ++r)
          Fp[pair * 4096 + (g * 16 + quad * 4 + r) * 64 + ctd * 16 + l16] = oacc[g][ctd][r];
#pragma unroll
      for (int r = 0; r < 4; ++r)
        Ls[pair * 64 + g * 16 + quad * 4 + r] = lacc[g][r];
    }
  }
  __syncthreads();
  if (kh == 0) {
    const int b = bh >> 4, h = bh & 15;
#pragma unroll
    for (int g = 0; g < 4; ++g)
#pragma unroll
      for (int r = 0; r < 4; ++r) {
        const int ql = g * 16 + quad * 4 + r;
        const float lv = lacc[g][r] + Ls[pair * 64 + ql];
        const float inv = 1.0f / lv;
        const int t = qt * 128 + pair * 64 + ql;
#pragma unroll
        for (int ctd = 0; ctd < 4; ++ctd) {
          const float val = oacc[g][ctd][r] + Fp[pair * 4096 + ql * 64 + ctd * 16 + l16];
          O[((size_t)t * 2 + b) * 1024 + h * 64 + ctd * 16 + l16] = cvt_bf16(val * inv);
        }
      }
  }
}

// ---------------- output projection GEMM (Wo fp32 in, cvt fused) ----------------
// R0 simple structure: 128x64 tile, BK=64, single-buffer LDS, two
// __syncthreads per K-step, 4 blocks/CU. A (Oa bf16) staged via gll16 with
// source-folded swizzle; B (Wo fp32) reg-staged with fused convert.
__global__ __launch_bounds__(256, 4) void gemm_out(
    const unsigned short* __restrict__ A,   // O: [4096][1024] bf16
    const float* __restrict__ Wf,           // Wo: [1024][1024] fp32
    const float* __restrict__ bias,         // [1024] fp32
    float* __restrict__ out)                // [4096][1024] fp32 = d_out
{
  __shared__ unsigned short As[128 * 64];   // 16 KB
  __shared__ unsigned short Bs[64 * 64];    // 8 KB
  const int tid = threadIdx.x;
  const int wave = tid >> 6, lane = tid & 63;
  const int quad = lane >> 4, l16 = lane & 15;
  const int flat = blockIdx.x + (blockIdx.y << 4);
  const int nf = (flat & 7) * 64 + (flat >> 3);
  const int m0 = (nf >> 4) * 128;
  const int n0 = (nf & 15) * 64;
  const unsigned short* Ab = A + (size_t)m0 * 1024;
  const float* Bb = Wf + (size_t)n0 * 1024;
  const int wr = (wave >> 1) * 64, wc = (wave & 1) * 32;

  const f32x4 z4 = {0.f, 0.f, 0.f, 0.f};
  f32x4 acc[4][2];
#pragma unroll
  for (int i = 0; i < 4; ++i)
#pragma unroll
    for (int j = 0; j < 2; ++j) acc[i][j] = z4;

  for (int k0 = 0; k0 < 1024; k0 += 64) {
    __syncthreads();
#pragma unroll
    for (int j = 0; j < 4; ++j) {          // A: 1024 chunks via DMA
      const int c = j * 256 + tid;
      const int row = c >> 3, pc = c & 7;
      const int kc = pc ^ (row & 7);
      gll16(Ab + (size_t)row * 1024 + k0 + kc * 8, &As[c * 8]);
    }
#pragma unroll
    for (int j = 0; j < 2; ++j) {          // B: 512 chunks, fp32 reg-staged
      const int c = j * 256 + tid;
      const int row = c >> 3, pc = c & 7;
      const float* sb = Bb + (size_t)row * 1024 + k0 + pc * 8;
      const float4 b0 = *(const float4*)sb;
      const float4 b1 = *(const float4*)(sb + 4);
      *(uint4*)&Bs[row * 64 + (pc ^ (row & 7)) * 8] = cvt8(b0, b1, 1.0f);
    }
    __syncthreads();
#pragma unroll
    for (int kk = 0; kk < 2; ++kk) {
      bf16x8 af[4], bfr[2];
#pragma unroll
      for (int rt = 0; rt < 4; ++rt) {
        const int row = wr + rt * 16 + l16;
        af[rt] = *(const bf16x8*)&As[row * 64 + ((kk * 4 + quad) ^ (row & 7)) * 8];
      }
#pragma unroll
      for (int ct = 0; ct < 2; ++ct) {
        const int row = wc + ct * 16 + l16;
        bfr[ct] = *(const bf16x8*)&Bs[row * 64 + ((kk * 4 + quad) ^ (row & 7)) * 8];
      }
#pragma unroll
      for (int rt = 0; rt < 4; ++rt)
#pragma unroll
        for (int ct = 0; ct < 2; ++ct)
          acc[rt][ct] = MFMA(af[rt], bfr[ct], acc[rt][ct]);
    }
  }

#pragma unroll
  for (int rt = 0; rt < 4; ++rt)
#pragma unroll
    for (int ct = 0; ct < 2; ++ct) {
      const int gn = n0 + wc + ct * 16 + l16;
      const float bv = bias[gn];
#pragma unroll
      for (int r = 0; r < 4; ++r) {
        const int gm = m0 + wr + rt * 16 + quad * 4 + r;
        out[(size_t)gm * 1024 + gn] = acc[rt][ct][r] + bv;
      }
    }
}

// ---------------- launch ----------------
extern "C" void kernel_launch(void* const* d_in, const int* in_sizes, int n_in,
                              void* d_out, int out_size, void* d_ws, size_t ws_size,
                              hipStream_t stream) {
  const float* q   = (const float*)d_in[0];
  const float* k   = (const float*)d_in[1];
  const float* v   = (const float*)d_in[2];
  const float* ipw = (const float*)d_in[3];
  const float* ipb = (const float*)d_in[4];
  const float* opw = (const float*)d_in[5];
  const float* opb = (const float*)d_in[6];

  unsigned short* ws = (unsigned short*)d_ws;
  unsigned short* Qh = ws;              // 32*2048*64 = 4194304
  unsigned short* Kh = ws + 4194304;
  unsigned short* Vx = ws + 8388608;    // V transposed+permuted
  unsigned short* Oa = ws + 12582912;

  gemm_qkv<<<dim3(8, 32, 3), 256, 0, stream>>>(q, k, v, ipw, ipb, Qh, Kh, Vx);
  attn<<<dim3(16, 32), 256, 0, stream>>>(Qh, Kh, Vx, Oa);
  gemm_out<<<dim3(16, 32), 256, 0, stream>>>(Oa, opw, opb, (float*)d_out);
}

// Round 7
// 216.608 us; speedup vs baseline: 1.0427x; 1.0427x over previous
//
#include <hip/hip_runtime.h>
#include <cstdint>
#include <cstddef>

// T=2048 B=2 E=1024 H=16 hd=64. M = T*B = 4096 rows.
// QSCALE = head_dim^-0.5 * log2(e), folded into wq + bq so softmax runs base-2.
#define QSCALE 0.18033688011112042f

typedef __attribute__((ext_vector_type(8))) short bf16x8;
typedef __attribute__((ext_vector_type(4))) float f32x4;

#define MFMA(a, b, c) __builtin_amdgcn_mfma_f32_16x16x32_bf16(a, b, c, 0, 0, 0)

// boundary sync (attn): drain this wave's DMA (issued >=1 compute-phase ago), barrier.
#define PIPE_SYNC() do {                                   \
    asm volatile("s_waitcnt vmcnt(0)" ::: "memory");       \
    __builtin_amdgcn_sched_barrier(0);                     \
    __builtin_amdgcn_s_barrier();                          \
    __builtin_amdgcn_sched_barrier(0);                     \
  } while (0)

typedef union { unsigned int u[4]; bf16x8 b; } pku;

__device__ __forceinline__ unsigned short cvt_bf16(float x) {
  union { float f; unsigned int u; } v;
  v.f = x;
  unsigned int r = v.u + 0x7FFFu + ((v.u >> 16) & 1u);  // RNE
  return (unsigned short)(r >> 16);
}

__device__ __forceinline__ void gll16(const void* g, void* l) {
  __builtin_amdgcn_global_load_lds(
      (const __attribute__((address_space(1))) unsigned int*)g,
      (__attribute__((address_space(3))) unsigned int*)l, 16, 0, 0);
}

__device__ __forceinline__ float fast_exp2(float x) {
#if __has_builtin(__builtin_amdgcn_exp2f)
  return __builtin_amdgcn_exp2f(x);
#else
  float r; asm("v_exp_f32 %0, %1" : "=v"(r) : "v"(x)); return r;
#endif
}

// pack two fp32 -> two bf16 (round-nearest, ties-away) in one v_perm_b32
__device__ __forceinline__ unsigned int pack_bf16(float lo, float hi) {
  union { float f; unsigned int u; } a, b;
  a.f = lo; b.f = hi;
  return __builtin_amdgcn_perm(b.u + 0x8000u, a.u + 0x8000u, 0x07060302u);
}

// ---------------- fp32 -> bf16 converts (single kernel) ----------------
__global__ void cvt_all(const float* __restrict__ q,
                        const float* __restrict__ k,
                        const float* __restrict__ v,
                        const float* __restrict__ ipw,
                        const float* __restrict__ opw,
                        unsigned short* __restrict__ dst) {
  const size_t i = ((size_t)blockIdx.x * 256 + threadIdx.x) * 8;
  const float* src;
  float scale = 1.0f;
  if (i < 4194304) src = q + i;
  else if (i < 8388608) src = k + (i - 4194304);
  else if (i < 12582912) src = v + (i - 8388608);
  else {
    const size_t w = i - 12582912;
    if (w < 3145728) { src = ipw + w; if (w < 1048576) scale = QSCALE; }
    else src = opw + (w - 3145728);
  }
  float4 a = *(const float4*)src;
  float4 b = *(const float4*)(src + 4);
  uint4 o;
  o.x = cvt_bf16(a.x * scale) | ((unsigned int)cvt_bf16(a.y * scale) << 16);
  o.y = cvt_bf16(a.z * scale) | ((unsigned int)cvt_bf16(a.w * scale) << 16);
  o.z = cvt_bf16(b.x * scale) | ((unsigned int)cvt_bf16(b.y * scale) << 16);
  o.w = cvt_bf16(b.z * scale) | ((unsigned int)cvt_bf16(b.w * scale) << 16);
  *(uint4*)(dst + i) = o;
}

// ---------------- QKV projection GEMM ----------------
// R0-exact restoration: 128x128 tile, BK=64, single 32 KB LDS, two
// __syncthreads per K-step, 3 blocks/CU. Best measured variant (48.6 us
// vs 52.6 dbuf-WBIC, 62.9 4-phase, 85+ fp32-fused).
__global__ __launch_bounds__(256, 3) void gemm_qkv(
    const unsigned short* __restrict__ X,   // [3][4096][1024] bf16
    const unsigned short* __restrict__ W,   // [3072][1024] bf16 (wq pre-scaled)
    const float* __restrict__ bias,         // [3072] fp32
    unsigned short* __restrict__ Qh,        // [32][2048][64]
    unsigned short* __restrict__ Kh,        // [32][2048][64]
    unsigned short* __restrict__ Vt)        // [32][64][2048] key-permuted
{
  __shared__ unsigned short As[128 * 64];   // 16 KB
  __shared__ unsigned short Bs[128 * 64];   // 16 KB
  const int tid = threadIdx.x;
  const int wave = tid >> 6, lane = tid & 63;
  const int quad = lane >> 4, l16 = lane & 15;
  const int flat = blockIdx.x + (blockIdx.y << 3) + (blockIdx.z << 8);
  const int nf = (flat & 7) * 96 + (flat >> 3);
  const int z = nf >> 8;
  const int m0 = ((nf >> 3) & 31) * 128;
  const int n0 = (nf & 7) * 128;
  const unsigned short* Ab = X + (size_t)z * 4194304 + (size_t)m0 * 1024;
  const unsigned short* Bb = W + ((size_t)z * 1024 + n0) * 1024;
  const int wr = (wave >> 1) * 64, wc = (wave & 1) * 64;

  const f32x4 z4 = {0.f, 0.f, 0.f, 0.f};
  f32x4 acc[4][4];
#pragma unroll
  for (int i = 0; i < 4; ++i)
#pragma unroll
    for (int j = 0; j < 4; ++j) acc[i][j] = z4;

  for (int k0 = 0; k0 < 1024; k0 += 64) {
    __syncthreads();
#pragma unroll
    for (int j = 0; j < 4; ++j) {
      const int c = j * 256 + tid;          // chunk 0..1023
      const int row = c >> 3, pc = c & 7;   // 8x16B chunks per 64-elem row
      const int kc = pc ^ (row & 7);        // swizzle folded into global src
      gll16(Ab + (size_t)row * 1024 + k0 + kc * 8, &As[c * 8]);
      gll16(Bb + (size_t)row * 1024 + k0 + kc * 8, &Bs[c * 8]);
    }
    __syncthreads();
#pragma unroll
    for (int kk = 0; kk < 2; ++kk) {
      bf16x8 af[4], bfr[4];
#pragma unroll
      for (int rt = 0; rt < 4; ++rt) {
        const int row = wr + rt * 16 + l16;
        af[rt] = *(const bf16x8*)&As[row * 64 + ((kk * 4 + quad) ^ (row & 7)) * 8];
      }
#pragma unroll
      for (int ct = 0; ct < 4; ++ct) {
        const int row = wc + ct * 16 + l16;
        bfr[ct] = *(const bf16x8*)&Bs[row * 64 + ((kk * 4 + quad) ^ (row & 7)) * 8];
      }
#pragma unroll
      for (int rt = 0; rt < 4; ++rt)
#pragma unroll
        for (int ct = 0; ct < 4; ++ct)
          acc[rt][ct] = MFMA(af[rt], bfr[ct], acc[rt][ct]);
    }
  }

#pragma unroll
  for (int rt = 0; rt < 4; ++rt)
#pragma unroll
    for (int ct = 0; ct < 4; ++ct) {
      const int gn = n0 + wc + ct * 16 + l16;
      float bv = bias[z * 1024 + gn];
      if (z == 0) bv *= QSCALE;
      const int h = gn >> 6, d = gn & 63;
#pragma unroll
      for (int r = 0; r < 4; ++r) {
        const int gm = m0 + wr + rt * 16 + quad * 4 + r;  // m = t*2 + b
        const int t = gm >> 1, b = gm & 1;
        const int bh = b * 16 + h;
        const unsigned short o = cvt_bf16(acc[rt][ct][r] + bv);
        if (z == 0)      Qh[((size_t)bh * 2048 + t) * 64 + d] = o;
        else if (z == 1) Kh[((size_t)bh * 2048 + t) * 64 + d] = o;
        else {
          const int w32 = t & 31;   // pi: {16hi+4q+r} -> q*8 + hi*4 + r
          const int tp = (t & ~31) | (((w32 >> 2) & 3) << 3) | ((w32 >> 4) << 2) | (w32 & 3);
          Vt[((size_t)bh * 64 + d) * 2048 + tp] = o;
        }
      }
    }
}

// ---------------- flash attention ----------------
// R5/R6-passing version, unchanged (race-screened across two benches):
// QBLK=128, 512 blocks = 2/CU, W-B-I-C dbuf, setprio around PV cluster.
__global__ __launch_bounds__(256, 2) void attn(
    const unsigned short* __restrict__ Qh,
    const unsigned short* __restrict__ Kh,
    const unsigned short* __restrict__ Vt,
    unsigned short* __restrict__ O)   // [4096][1024] bf16 (row = t*2+b)
{
  __shared__ unsigned short KV[2][16384];  // 64 KB: per buf Ks [128][64] | Vs [64][128]
  __shared__ float Ls[128];                // pair-combine l partials
  const int tid = threadIdx.x;
  const int wave = tid >> 6, lane = tid & 63;
  const int quad = lane >> 4, l16 = lane & 15;
  const int pair = wave >> 1, kh = wave & 1;
  const int flat = blockIdx.x + (blockIdx.y << 4);   // grid (16,32)
  const int nf = (flat & 7) * 64 + (flat >> 3);      // XCD j: 4 whole bh's
  const int qt = nf & 15, bh = nf >> 4;
  const unsigned short* Qb = Qh + ((size_t)bh * 2048 + qt * 128 + pair * 64) * 64;
  const unsigned short* Kb = Kh + (size_t)bh * 2048 * 64;
  const unsigned short* Vb = Vt + (size_t)bh * 64 * 2048;

  bf16x8 qf[4][2];  // B-frags for S^T = K.Q^T; 4 q-groups of 16 rows
#pragma unroll
  for (int g = 0; g < 4; ++g)
#pragma unroll
    for (int kk = 0; kk < 2; ++kk)
      qf[g][kk] = *(const bf16x8*)(Qb + (size_t)(g * 16 + l16) * 64 + kk * 32 + quad * 8);

  const unsigned short* kp[4];
  const unsigned short* vp[4];
  int klo[4], vlo[4];
#pragma unroll
  for (int j = 0; j < 4; ++j) {
    const int c = wave * 256 + j * 64 + lane;   // chunk 0..1023
    const int r = c >> 3, cc = c & 7;
    kp[j] = Kb + (size_t)r * 64 + (cc ^ (r & 7)) * 8;
    klo[j] = c * 8;
    const int r2 = c >> 4, cc2 = c & 15;
    vp[j] = Vb + (size_t)r2 * 2048 + (cc2 ^ (r2 & 15)) * 8;
    vlo[j] = 8192 + c * 8;
  }

  pku ones;
  ones.u[0] = ones.u[1] = ones.u[2] = ones.u[3] = 0x3F803F80u;  // bf16 1.0 x8

  const f32x4 z4 = {0.f, 0.f, 0.f, 0.f};
  f32x4 oacc[4][4];
  f32x4 lacc[4] = {z4, z4, z4, z4};
#pragma unroll
  for (int g = 0; g < 4; ++g)
#pragma unroll
    for (int c = 0; c < 4; ++c) oacc[g][c] = z4;

#pragma unroll
  for (int j = 0; j < 4; ++j) {
    gll16(kp[j], &KV[0][klo[j]]);
    gll16(vp[j], &KV[0][vlo[j]]);
    kp[j] += 128 * 64;
    vp[j] += 128;
  }

#pragma unroll 1
  for (int it = 0; it < 16; ++it) {
    const int cur = it & 1;
    PIPE_SYNC();         // T(it) landed everywhere; buf[cur^1] free
    if (it < 15) {
#pragma unroll
      for (int j = 0; j < 4; ++j) {
        gll16(kp[j], &KV[cur ^ 1][klo[j]]);
        gll16(vp[j], &KV[cur ^ 1][vlo[j]]);
        kp[j] += 128 * 64;
        vp[j] += 128;
      }
    }
    const unsigned short* Ks = KV[cur];
    const unsigned short* Vs = KV[cur] + 8192;

#pragma unroll
    for (int jj = 0; jj < 2; ++jj) {
      unsigned int pk0[4][2], pk1[4][2];
#pragma unroll
      for (int half = 0; half < 2; ++half) {
        const int ct = jj * 2 + half;
        const int R = kh * 64 + ct * 16 + l16;
        bf16x8 kfr[2];
#pragma unroll
        for (int kk = 0; kk < 2; ++kk)
          kfr[kk] = *(const bf16x8*)&Ks[R * 64 + ((kk * 4 + quad) ^ (R & 7)) * 8];
#pragma unroll
        for (int g = 0; g < 4; ++g) {
          f32x4 sv = z4;
          sv = MFMA(kfr[0], qf[g][0], sv);
          sv = MFMA(kfr[1], qf[g][1], sv);
          f32x4 p;
#pragma unroll
          for (int r = 0; r < 4; ++r) p[r] = fast_exp2(sv[r]);
          pk0[g][half] = pack_bf16(p[0], p[1]);
          pk1[g][half] = pack_bf16(p[2], p[3]);
        }
      }
      const int jjg = kh * 2 + jj;
      __builtin_amdgcn_s_setprio(1);
#pragma unroll
      for (int ctd = 0; ctd < 4; ++ctd) {
        const int R = ctd * 16 + l16;
        const int phys = (jjg * 4 + quad) ^ (R & 15);
        const bf16x8 vv = *(const bf16x8*)&Vs[R * 128 + phys * 8];
#pragma unroll
        for (int g = 0; g < 4; ++g) {
          pku a;
          a.u[0] = pk0[g][0]; a.u[1] = pk1[g][0];
          a.u[2] = pk0[g][1]; a.u[3] = pk1[g][1];
          oacc[g][ctd] = MFMA(a.b, vv, oacc[g][ctd]);
        }
      }
#pragma unroll
      for (int g = 0; g < 4; ++g) {
        pku a;
        a.u[0] = pk0[g][0]; a.u[1] = pk1[g][0];
        a.u[2] = pk0[g][1]; a.u[3] = pk1[g][1];
        lacc[g] = MFMA(a.b, ones.b, lacc[g]);
      }
      __builtin_amdgcn_s_setprio(0);
    }
  }

  __syncthreads();
  float* Fp = (float*)KV;               // pair region: pair*4096 floats [q][d]
  if (kh == 1) {
#pragma unroll
    for (int g = 0; g < 4; ++g) {
#pragma unroll
      for (int ctd = 0; ctd < 4; ++ctd)
#pragma unroll
        for (int r = 0; r < 4; ++r)
          Fp[pair * 4096 + (g * 16 + quad * 4 + r) * 64 + ctd * 16 + l16] = oacc[g][ctd][r];
#pragma unroll
      for (int r = 0; r < 4; ++r)
        Ls[pair * 64 + g * 16 + quad * 4 + r] = lacc[g][r];
    }
  }
  __syncthreads();
  if (kh == 0) {
    const int b = bh >> 4, h = bh & 15;
#pragma unroll
    for (int g = 0; g < 4; ++g)
#pragma unroll
      for (int r = 0; r < 4; ++r) {
        const int ql = g * 16 + quad * 4 + r;
        const float lv = lacc[g][r] + Ls[pair * 64 + ql];
        const float inv = 1.0f / lv;
        const int t = qt * 128 + pair * 64 + ql;
#pragma unroll
        for (int ctd = 0; ctd < 4; ++ctd) {
          const float val = oacc[g][ctd][r] + Fp[pair * 4096 + ql * 64 + ctd * 16 + l16];
          O[((size_t)t * 2 + b) * 1024 + h * 64 + ctd * 16 + l16] = cvt_bf16(val * inv);
        }
      }
  }
}

// ---------------- output projection GEMM ----------------
// THIS ROUND: tile 128x64 -> 64x64, grid 512 -> 1024 blocks = 4 blocks/CU
// (16 waves/CU TLP to hide staging bursts; structure unchanged 2-barrier).
// B re-reads stay L2-resident (Wo = 2 MB bf16).
__global__ __launch_bounds__(256, 4) void gemm_out(
    const unsigned short* __restrict__ A,   // O: [4096][1024] bf16
    const unsigned short* __restrict__ W,   // Wo: [1024][1024] bf16
    const float* __restrict__ bias,         // [1024] fp32
    float* __restrict__ out)                // [4096][1024] fp32 = d_out
{
  __shared__ unsigned short As[64 * 64];    // 8 KB
  __shared__ unsigned short Bs[64 * 64];    // 8 KB
  const int tid = threadIdx.x;
  const int wave = tid >> 6, lane = tid & 63;
  const int quad = lane >> 4, l16 = lane & 15;
  const int flat = blockIdx.x + (blockIdx.y << 5);   // grid (32,32) = 1024
  const int nf = (flat & 7) * 128 + (flat >> 3);     // XCD remap
  const int m0 = (nf >> 4) * 64;                     // 64 m-tiles
  const int n0 = (nf & 15) * 64;                     // 16 n-tiles
  const unsigned short* Ab = A + (size_t)m0 * 1024;
  const unsigned short* Bb = W + (size_t)n0 * 1024;
  const int wr = (wave >> 1) * 32, wc = (wave & 1) * 32;

  const f32x4 z4 = {0.f, 0.f, 0.f, 0.f};
  f32x4 acc[2][2];
#pragma unroll
  for (int i = 0; i < 2; ++i)
#pragma unroll
    for (int j = 0; j < 2; ++j) acc[i][j] = z4;

  for (int k0 = 0; k0 < 1024; k0 += 64) {
    __syncthreads();
#pragma unroll
    for (int j = 0; j < 2; ++j) {          // A: 512 chunks
      const int c = j * 256 + tid;
      const int row = c >> 3, pc = c & 7;
      const int kc = pc ^ (row & 7);
      gll16(Ab + (size_t)row * 1024 + k0 + kc * 8, &As[c * 8]);
    }
#pragma unroll
    for (int j = 0; j < 2; ++j) {          // B: 512 chunks
      const int c = j * 256 + tid;
      const int row = c >> 3, pc = c & 7;
      const int kc = pc ^ (row & 7);
      gll16(Bb + (size_t)row * 1024 + k0 + kc * 8, &Bs[c * 8]);
    }
    __syncthreads();
#pragma unroll
    for (int kk = 0; kk < 2; ++kk) {
      bf16x8 af[2], bfr[2];
#pragma unroll
      for (int rt = 0; rt < 2; ++rt) {
        const int row = wr + rt * 16 + l16;
        af[rt] = *(const bf16x8*)&As[row * 64 + ((kk * 4 + quad) ^ (row & 7)) * 8];
      }
#pragma unroll
      for (int ct = 0; ct < 2; ++ct) {
        const int row = wc + ct * 16 + l16;
        bfr[ct] = *(const bf16x8*)&Bs[row * 64 + ((kk * 4 + quad) ^ (row & 7)) * 8];
      }
#pragma unroll
      for (int rt = 0; rt < 2; ++rt)
#pragma unroll
        for (int ct = 0; ct < 2; ++ct)
          acc[rt][ct] = MFMA(af[rt], bfr[ct], acc[rt][ct]);
    }
  }

#pragma unroll
  for (int rt = 0; rt < 2; ++rt)
#pragma unroll
    for (int ct = 0; ct < 2; ++ct) {
      const int gn = n0 + wc + ct * 16 + l16;
      const float bv = bias[gn];
#pragma unroll
      for (int r = 0; r < 4; ++r) {
        const int gm = m0 + wr + rt * 16 + quad * 4 + r;
        out[(size_t)gm * 1024 + gn] = acc[rt][ct][r] + bv;
      }
    }
}

// ---------------- launch ----------------
extern "C" void kernel_launch(void* const* d_in, const int* in_sizes, int n_in,
                              void* d_out, int out_size, void* d_ws, size_t ws_size,
                              hipStream_t stream) {
  const float* q   = (const float*)d_in[0];
  const float* k   = (const float*)d_in[1];
  const float* v   = (const float*)d_in[2];
  const float* ipw = (const float*)d_in[3];
  const float* ipb = (const float*)d_in[4];
  const float* opw = (const float*)d_in[5];
  const float* opb = (const float*)d_in[6];

  unsigned short* ws = (unsigned short*)d_ws;
  unsigned short* X  = ws;              // 3 * 4096*1024      = 12582912
  unsigned short* Wb = ws + 12582912;   // 3072*1024          =  3145728
  unsigned short* Wo = ws + 15728640;   // 1024*1024          =  1048576
  unsigned short* Qh = ws + 16777216;   // 32*2048*64         =  4194304
  unsigned short* Kh = ws + 20971520;   //                       4194304
  unsigned short* Vx = ws + 25165824;   // V transposed+permuted 4194304
  unsigned short* Oa = ws + 29360128;   //                       4194304

  cvt_all<<<dim3(8192), 256, 0, stream>>>(q, k, v, ipw, opw, ws);
  gemm_qkv<<<dim3(8, 32, 3), 256, 0, stream>>>(X, Wb, ipb, Qh, Kh, Vx);
  attn<<<dim3(16, 32), 256, 0, stream>>>(Qh, Kh, Vx, Oa);
  gemm_out<<<dim3(32, 32), 256, 0, stream>>>(Oa, Wo, opb, (float*)d_out);
}

// Round 8
// 209.810 us; speedup vs baseline: 1.0764x; 1.0324x over previous
//
#include <hip/hip_runtime.h>
#include <cstdint>
#include <cstddef>

// T=2048 B=2 E=1024 H=16 hd=64. M = T*B = 4096 rows.
// QSCALE = head_dim^-0.5 * log2(e), folded into wq + bq so softmax runs base-2.
#define QSCALE 0.18033688011112042f

typedef __attribute__((ext_vector_type(8))) short bf16x8;
typedef __attribute__((ext_vector_type(4))) float f32x4;

#define MFMA(a, b, c) __builtin_amdgcn_mfma_f32_16x16x32_bf16(a, b, c, 0, 0, 0)

// boundary sync (attn): drain this wave's DMA (issued >=1 compute-phase ago), barrier.
#define PIPE_SYNC() do {                                   \
    asm volatile("s_waitcnt vmcnt(0)" ::: "memory");       \
    __builtin_amdgcn_sched_barrier(0);                     \
    __builtin_amdgcn_s_barrier();                          \
    __builtin_amdgcn_sched_barrier(0);                     \
  } while (0)

typedef union { unsigned int u[4]; bf16x8 b; } pku;

__device__ __forceinline__ unsigned short cvt_bf16(float x) {
  union { float f; unsigned int u; } v;
  v.f = x;
  unsigned int r = v.u + 0x7FFFu + ((v.u >> 16) & 1u);  // RNE
  return (unsigned short)(r >> 16);
}

__device__ __forceinline__ void gll16(const void* g, void* l) {
  __builtin_amdgcn_global_load_lds(
      (const __attribute__((address_space(1))) unsigned int*)g,
      (__attribute__((address_space(3))) unsigned int*)l, 16, 0, 0);
}

__device__ __forceinline__ float fast_exp2(float x) {
#if __has_builtin(__builtin_amdgcn_exp2f)
  return __builtin_amdgcn_exp2f(x);
#else
  float r; asm("v_exp_f32 %0, %1" : "=v"(r) : "v"(x)); return r;
#endif
}

// pack two fp32 -> two bf16 (round-nearest, ties-away) in one v_perm_b32
__device__ __forceinline__ unsigned int pack_bf16(float lo, float hi) {
  union { float f; unsigned int u; } a, b;
  a.f = lo; b.f = hi;
  return __builtin_amdgcn_perm(b.u + 0x8000u, a.u + 0x8000u, 0x07060302u);
}

// ---------------- fp32 -> bf16 converts (single kernel) ----------------
__global__ void cvt_all(const float* __restrict__ q,
                        const float* __restrict__ k,
                        const float* __restrict__ v,
                        const float* __restrict__ ipw,
                        const float* __restrict__ opw,
                        unsigned short* __restrict__ dst) {
  const size_t i = ((size_t)blockIdx.x * 256 + threadIdx.x) * 8;
  const float* src;
  float scale = 1.0f;
  if (i < 4194304) src = q + i;
  else if (i < 8388608) src = k + (i - 4194304);
  else if (i < 12582912) src = v + (i - 8388608);
  else {
    const size_t w = i - 12582912;
    if (w < 3145728) { src = ipw + w; if (w < 1048576) scale = QSCALE; }
    else src = opw + (w - 3145728);
  }
  float4 a = *(const float4*)src;
  float4 b = *(const float4*)(src + 4);
  uint4 o;
  o.x = cvt_bf16(a.x * scale) | ((unsigned int)cvt_bf16(a.y * scale) << 16);
  o.y = cvt_bf16(a.z * scale) | ((unsigned int)cvt_bf16(a.w * scale) << 16);
  o.z = cvt_bf16(b.x * scale) | ((unsigned int)cvt_bf16(b.y * scale) << 16);
  o.w = cvt_bf16(b.z * scale) | ((unsigned int)cvt_bf16(b.w * scale) << 16);
  *(uint4*)(dst + i) = o;
}

// ---------------- QKV projection GEMM ----------------
// R0-exact (best measured: 48.6 us): 128x128 tile, BK=64, single 32 KB LDS,
// two __syncthreads per K-step, 3 blocks/CU, XOR-swizzled LDS, XCD remap.
__global__ __launch_bounds__(256, 3) void gemm_qkv(
    const unsigned short* __restrict__ X,   // [3][4096][1024] bf16
    const unsigned short* __restrict__ W,   // [3072][1024] bf16 (wq pre-scaled)
    const float* __restrict__ bias,         // [3072] fp32
    unsigned short* __restrict__ Qh,        // [32][2048][64]
    unsigned short* __restrict__ Kh,        // [32][2048][64]
    unsigned short* __restrict__ Vt)        // [32][64][2048] key-permuted
{
  __shared__ unsigned short As[128 * 64];   // 16 KB
  __shared__ unsigned short Bs[128 * 64];   // 16 KB
  const int tid = threadIdx.x;
  const int wave = tid >> 6, lane = tid & 63;
  const int quad = lane >> 4, l16 = lane & 15;
  const int flat = blockIdx.x + (blockIdx.y << 3) + (blockIdx.z << 8);
  const int nf = (flat & 7) * 96 + (flat >> 3);
  const int z = nf >> 8;
  const int m0 = ((nf >> 3) & 31) * 128;
  const int n0 = (nf & 7) * 128;
  const unsigned short* Ab = X + (size_t)z * 4194304 + (size_t)m0 * 1024;
  const unsigned short* Bb = W + ((size_t)z * 1024 + n0) * 1024;
  const int wr = (wave >> 1) * 64, wc = (wave & 1) * 64;

  const f32x4 z4 = {0.f, 0.f, 0.f, 0.f};
  f32x4 acc[4][4];
#pragma unroll
  for (int i = 0; i < 4; ++i)
#pragma unroll
    for (int j = 0; j < 4; ++j) acc[i][j] = z4;

  for (int k0 = 0; k0 < 1024; k0 += 64) {
    __syncthreads();
#pragma unroll
    for (int j = 0; j < 4; ++j) {
      const int c = j * 256 + tid;          // chunk 0..1023
      const int row = c >> 3, pc = c & 7;   // 8x16B chunks per 64-elem row
      const int kc = pc ^ (row & 7);        // swizzle folded into global src
      gll16(Ab + (size_t)row * 1024 + k0 + kc * 8, &As[c * 8]);
      gll16(Bb + (size_t)row * 1024 + k0 + kc * 8, &Bs[c * 8]);
    }
    __syncthreads();
#pragma unroll
    for (int kk = 0; kk < 2; ++kk) {
      bf16x8 af[4], bfr[4];
#pragma unroll
      for (int rt = 0; rt < 4; ++rt) {
        const int row = wr + rt * 16 + l16;
        af[rt] = *(const bf16x8*)&As[row * 64 + ((kk * 4 + quad) ^ (row & 7)) * 8];
      }
#pragma unroll
      for (int ct = 0; ct < 4; ++ct) {
        const int row = wc + ct * 16 + l16;
        bfr[ct] = *(const bf16x8*)&Bs[row * 64 + ((kk * 4 + quad) ^ (row & 7)) * 8];
      }
#pragma unroll
      for (int rt = 0; rt < 4; ++rt)
#pragma unroll
        for (int ct = 0; ct < 4; ++ct)
          acc[rt][ct] = MFMA(af[rt], bfr[ct], acc[rt][ct]);
    }
  }

#pragma unroll
  for (int rt = 0; rt < 4; ++rt)
#pragma unroll
    for (int ct = 0; ct < 4; ++ct) {
      const int gn = n0 + wc + ct * 16 + l16;
      float bv = bias[z * 1024 + gn];
      if (z == 0) bv *= QSCALE;
      const int h = gn >> 6, d = gn & 63;
#pragma unroll
      for (int r = 0; r < 4; ++r) {
        const int gm = m0 + wr + rt * 16 + quad * 4 + r;  // m = t*2 + b
        const int t = gm >> 1, b = gm & 1;
        const int bh = b * 16 + h;
        const unsigned short o = cvt_bf16(acc[rt][ct][r] + bv);
        if (z == 0)      Qh[((size_t)bh * 2048 + t) * 64 + d] = o;
        else if (z == 1) Kh[((size_t)bh * 2048 + t) * 64 + d] = o;
        else {
          const int w32 = t & 31;   // pi: {16hi+4q+r} -> q*8 + hi*4 + r
          const int tp = (t & ~31) | (((w32 >> 2) & 3) << 3) | ((w32 >> 4) << 2) | (w32 & 3);
          Vt[((size_t)bh * 64 + d) * 2048 + tp] = o;
        }
      }
    }
}

// ---------------- flash attention ----------------
// R7-passing version, unchanged (best measured: 48.4 us, three clean benches):
// QBLK=128, 512 blocks = 2/CU, W-B-I-C dbuf, setprio around PV cluster.
__global__ __launch_bounds__(256, 2) void attn(
    const unsigned short* __restrict__ Qh,
    const unsigned short* __restrict__ Kh,
    const unsigned short* __restrict__ Vt,
    unsigned short* __restrict__ O)   // [4096][1024] bf16 (row = t*2+b)
{
  __shared__ unsigned short KV[2][16384];  // 64 KB: per buf Ks [128][64] | Vs [64][128]
  __shared__ float Ls[128];                // pair-combine l partials
  const int tid = threadIdx.x;
  const int wave = tid >> 6, lane = tid & 63;
  const int quad = lane >> 4, l16 = lane & 15;
  const int pair = wave >> 1, kh = wave & 1;
  const int flat = blockIdx.x + (blockIdx.y << 4);   // grid (16,32)
  const int nf = (flat & 7) * 64 + (flat >> 3);      // XCD j: 4 whole bh's
  const int qt = nf & 15, bh = nf >> 4;
  const unsigned short* Qb = Qh + ((size_t)bh * 2048 + qt * 128 + pair * 64) * 64;
  const unsigned short* Kb = Kh + (size_t)bh * 2048 * 64;
  const unsigned short* Vb = Vt + (size_t)bh * 64 * 2048;

  bf16x8 qf[4][2];  // B-frags for S^T = K.Q^T; 4 q-groups of 16 rows
#pragma unroll
  for (int g = 0; g < 4; ++g)
#pragma unroll
    for (int kk = 0; kk < 2; ++kk)
      qf[g][kk] = *(const bf16x8*)(Qb + (size_t)(g * 16 + l16) * 64 + kk * 32 + quad * 8);

  const unsigned short* kp[4];
  const unsigned short* vp[4];
  int klo[4], vlo[4];
#pragma unroll
  for (int j = 0; j < 4; ++j) {
    const int c = wave * 256 + j * 64 + lane;   // chunk 0..1023
    const int r = c >> 3, cc = c & 7;
    kp[j] = Kb + (size_t)r * 64 + (cc ^ (r & 7)) * 8;
    klo[j] = c * 8;
    const int r2 = c >> 4, cc2 = c & 15;
    vp[j] = Vb + (size_t)r2 * 2048 + (cc2 ^ (r2 & 15)) * 8;
    vlo[j] = 8192 + c * 8;
  }

  pku ones;
  ones.u[0] = ones.u[1] = ones.u[2] = ones.u[3] = 0x3F803F80u;  // bf16 1.0 x8

  const f32x4 z4 = {0.f, 0.f, 0.f, 0.f};
  f32x4 oacc[4][4];
  f32x4 lacc[4] = {z4, z4, z4, z4};
#pragma unroll
  for (int g = 0; g < 4; ++g)
#pragma unroll
    for (int c = 0; c < 4; ++c) oacc[g][c] = z4;

#pragma unroll
  for (int j = 0; j < 4; ++j) {
    gll16(kp[j], &KV[0][klo[j]]);
    gll16(vp[j], &KV[0][vlo[j]]);
    kp[j] += 128 * 64;
    vp[j] += 128;
  }

#pragma unroll 1
  for (int it = 0; it < 16; ++it) {
    const int cur = it & 1;
    PIPE_SYNC();         // T(it) landed everywhere; buf[cur^1] free
    if (it < 15) {
#pragma unroll
      for (int j = 0; j < 4; ++j) {
        gll16(kp[j], &KV[cur ^ 1][klo[j]]);
        gll16(vp[j], &KV[cur ^ 1][vlo[j]]);
        kp[j] += 128 * 64;
        vp[j] += 128;
      }
    }
    const unsigned short* Ks = KV[cur];
    const unsigned short* Vs = KV[cur] + 8192;

#pragma unroll
    for (int jj = 0; jj < 2; ++jj) {
      unsigned int pk0[4][2], pk1[4][2];
#pragma unroll
      for (int half = 0; half < 2; ++half) {
        const int ct = jj * 2 + half;
        const int R = kh * 64 + ct * 16 + l16;
        bf16x8 kfr[2];
#pragma unroll
        for (int kk = 0; kk < 2; ++kk)
          kfr[kk] = *(const bf16x8*)&Ks[R * 64 + ((kk * 4 + quad) ^ (R & 7)) * 8];
#pragma unroll
        for (int g = 0; g < 4; ++g) {
          f32x4 sv = z4;
          sv = MFMA(kfr[0], qf[g][0], sv);
          sv = MFMA(kfr[1], qf[g][1], sv);
          f32x4 p;
#pragma unroll
          for (int r = 0; r < 4; ++r) p[r] = fast_exp2(sv[r]);
          pk0[g][half] = pack_bf16(p[0], p[1]);
          pk1[g][half] = pack_bf16(p[2], p[3]);
        }
      }
      const int jjg = kh * 2 + jj;
      __builtin_amdgcn_s_setprio(1);
#pragma unroll
      for (int ctd = 0; ctd < 4; ++ctd) {
        const int R = ctd * 16 + l16;
        const int phys = (jjg * 4 + quad) ^ (R & 15);
        const bf16x8 vv = *(const bf16x8*)&Vs[R * 128 + phys * 8];
#pragma unroll
        for (int g = 0; g < 4; ++g) {
          pku a;
          a.u[0] = pk0[g][0]; a.u[1] = pk1[g][0];
          a.u[2] = pk0[g][1]; a.u[3] = pk1[g][1];
          oacc[g][ctd] = MFMA(a.b, vv, oacc[g][ctd]);
        }
      }
#pragma unroll
      for (int g = 0; g < 4; ++g) {
        pku a;
        a.u[0] = pk0[g][0]; a.u[1] = pk1[g][0];
        a.u[2] = pk0[g][1]; a.u[3] = pk1[g][1];
        lacc[g] = MFMA(a.b, ones.b, lacc[g]);
      }
      __builtin_amdgcn_s_setprio(0);
    }
  }

  __syncthreads();
  float* Fp = (float*)KV;               // pair region: pair*4096 floats [q][d]
  if (kh == 1) {
#pragma unroll
    for (int g = 0; g < 4; ++g) {
#pragma unroll
      for (int ctd = 0; ctd < 4; ++ctd)
#pragma unroll
        for (int r = 0; r < 4; ++r)
          Fp[pair * 4096 + (g * 16 + quad * 4 + r) * 64 + ctd * 16 + l16] = oacc[g][ctd][r];
#pragma unroll
      for (int r = 0; r < 4; ++r)
        Ls[pair * 64 + g * 16 + quad * 4 + r] = lacc[g][r];
    }
  }
  __syncthreads();
  if (kh == 0) {
    const int b = bh >> 4, h = bh & 15;
#pragma unroll
    for (int g = 0; g < 4; ++g)
#pragma unroll
      for (int r = 0; r < 4; ++r) {
        const int ql = g * 16 + quad * 4 + r;
        const float lv = lacc[g][r] + Ls[pair * 64 + ql];
        const float inv = 1.0f / lv;
        const int t = qt * 128 + pair * 64 + ql;
#pragma unroll
        for (int ctd = 0; ctd < 4; ++ctd) {
          const float val = oacc[g][ctd][r] + Fp[pair * 4096 + ql * 64 + ctd * 16 + l16];
          O[((size_t)t * 2 + b) * 1024 + h * 64 + ctd * 16 + l16] = cvt_bf16(val * inv);
        }
      }
  }
}

// ---------------- output projection GEMM ----------------
// R0-exact restoration (part of the 210.5 us best config; the 64x64 retile
// measured -7 us WORSE in R7): 128x64 tile, BK=64, single-buffer LDS, two
// __syncthreads per K-step, grid 512, XCD remap.
__global__ __launch_bounds__(256, 4) void gemm_out(
    const unsigned short* __restrict__ A,   // O: [4096][1024] bf16
    const unsigned short* __restrict__ W,   // Wo: [1024][1024] bf16
    const float* __restrict__ bias,         // [1024] fp32
    float* __restrict__ out)                // [4096][1024] fp32 = d_out
{
  __shared__ unsigned short As[128 * 64];   // 16 KB
  __shared__ unsigned short Bs[64 * 64];    // 8 KB
  const int tid = threadIdx.x;
  const int wave = tid >> 6, lane = tid & 63;
  const int quad = lane >> 4, l16 = lane & 15;
  const int flat = blockIdx.x + (blockIdx.y << 4);
  const int nf = (flat & 7) * 64 + (flat >> 3);
  const int m0 = (nf >> 4) * 128;
  const int n0 = (nf & 15) * 64;
  const unsigned short* Ab = A + (size_t)m0 * 1024;
  const unsigned short* Bb = W + (size_t)n0 * 1024;
  const int wr = (wave >> 1) * 64, wc = (wave & 1) * 32;

  const f32x4 z4 = {0.f, 0.f, 0.f, 0.f};
  f32x4 acc[4][2];
#pragma unroll
  for (int i = 0; i < 4; ++i)
#pragma unroll
    for (int j = 0; j < 2; ++j) acc[i][j] = z4;

  for (int k0 = 0; k0 < 1024; k0 += 64) {
    __syncthreads();
#pragma unroll
    for (int j = 0; j < 4; ++j) {          // A: 1024 chunks
      const int c = j * 256 + tid;
      const int row = c >> 3, pc = c & 7;
      const int kc = pc ^ (row & 7);
      gll16(Ab + (size_t)row * 1024 + k0 + kc * 8, &As[c * 8]);
    }
#pragma unroll
    for (int j = 0; j < 2; ++j) {          // B: 512 chunks
      const int c = j * 256 + tid;
      const int row = c >> 3, pc = c & 7;
      const int kc = pc ^ (row & 7);
      gll16(Bb + (size_t)row * 1024 + k0 + kc * 8, &Bs[c * 8]);
    }
    __syncthreads();
#pragma unroll
    for (int kk = 0; kk < 2; ++kk) {
      bf16x8 af[4], bfr[2];
#pragma unroll
      for (int rt = 0; rt < 4; ++rt) {
        const int row = wr + rt * 16 + l16;
        af[rt] = *(const bf16x8*)&As[row * 64 + ((kk * 4 + quad) ^ (row & 7)) * 8];
      }
#pragma unroll
      for (int ct = 0; ct < 2; ++ct) {
        const int row = wc + ct * 16 + l16;
        bfr[ct] = *(const bf16x8*)&Bs[row * 64 + ((kk * 4 + quad) ^ (row & 7)) * 8];
      }
#pragma unroll
      for (int rt = 0; rt < 4; ++rt)
#pragma unroll
        for (int ct = 0; ct < 2; ++ct)
          acc[rt][ct] = MFMA(af[rt], bfr[ct], acc[rt][ct]);
    }
  }

#pragma unroll
  for (int rt = 0; rt < 4; ++rt)
#pragma unroll
    for (int ct = 0; ct < 2; ++ct) {
      const int gn = n0 + wc + ct * 16 + l16;
      const float bv = bias[gn];
#pragma unroll
      for (int r = 0; r < 4; ++r) {
        const int gm = m0 + wr + rt * 16 + quad * 4 + r;
        out[(size_t)gm * 1024 + gn] = acc[rt][ct][r] + bv;
      }
    }
}

// ---------------- launch ----------------
extern "C" void kernel_launch(void* const* d_in, const int* in_sizes, int n_in,
                              void* d_out, int out_size, void* d_ws, size_t ws_size,
                              hipStream_t stream) {
  const float* q   = (const float*)d_in[0];
  const float* k   = (const float*)d_in[1];
  const float* v   = (const float*)d_in[2];
  const float* ipw = (const float*)d_in[3];
  const float* ipb = (const float*)d_in[4];
  const float* opw = (const float*)d_in[5];
  const float* opb = (const float*)d_in[6];

  unsigned short* ws = (unsigned short*)d_ws;
  unsigned short* X  = ws;              // 3 * 4096*1024      = 12582912
  unsigned short* Wb = ws + 12582912;   // 3072*1024          =  3145728
  unsigned short* Wo = ws + 15728640;   // 1024*1024          =  1048576
  unsigned short* Qh = ws + 16777216;   // 32*2048*64         =  4194304
  unsigned short* Kh = ws + 20971520;   //                       4194304
  unsigned short* Vx = ws + 25165824;   // V transposed+permuted 4194304
  unsigned short* Oa = ws + 29360128;   //                       4194304

  cvt_all<<<dim3(8192), 256, 0, stream>>>(q, k, v, ipw, opw, ws);
  gemm_qkv<<<dim3(8, 32, 3), 256, 0, stream>>>(X, Wb, ipb, Qh, Kh, Vx);
  attn<<<dim3(16, 32), 256, 0, stream>>>(Qh, Kh, Vx, Oa);
  gemm_out<<<dim3(16, 32), 256, 0, stream>>>(Oa, Wo, opb, (float*)d_out);
}

// Round 9
// 208.264 us; speedup vs baseline: 1.0844x; 1.0074x over previous
//
#include <hip/hip_runtime.h>
#include <cstdint>
#include <cstddef>

// T=2048 B=2 E=1024 H=16 hd=64. M = T*B = 4096 rows.
// QSCALE = head_dim^-0.5 * log2(e), folded into wq + bq so softmax runs base-2.
#define QSCALE 0.18033688011112042f

typedef __attribute__((ext_vector_type(8))) short bf16x8;
typedef __attribute__((ext_vector_type(4))) float f32x4;

#define MFMA(a, b, c) __builtin_amdgcn_mfma_f32_16x16x32_bf16(a, b, c, 0, 0, 0)

// boundary sync (attn): drain this wave's DMA (issued >=1 compute-phase ago), barrier.
#define PIPE_SYNC() do {                                   \
    asm volatile("s_waitcnt vmcnt(0)" ::: "memory");       \
    __builtin_amdgcn_sched_barrier(0);                     \
    __builtin_amdgcn_s_barrier();                          \
    __builtin_amdgcn_sched_barrier(0);                     \
  } while (0)

typedef union { unsigned int u[4]; bf16x8 b; } pku;

__device__ __forceinline__ unsigned short cvt_bf16(float x) {
  union { float f; unsigned int u; } v;
  v.f = x;
  unsigned int r = v.u + 0x7FFFu + ((v.u >> 16) & 1u);  // RNE
  return (unsigned short)(r >> 16);
}

__device__ __forceinline__ void gll16(const void* g, void* l) {
  __builtin_amdgcn_global_load_lds(
      (const __attribute__((address_space(1))) unsigned int*)g,
      (__attribute__((address_space(3))) unsigned int*)l, 16, 0, 0);
}

__device__ __forceinline__ float fast_exp2(float x) {
#if __has_builtin(__builtin_amdgcn_exp2f)
  return __builtin_amdgcn_exp2f(x);
#else
  float r; asm("v_exp_f32 %0, %1" : "=v"(r) : "v"(x)); return r;
#endif
}

// pack two fp32 -> two bf16 (round-nearest, ties-away) in one v_perm_b32
__device__ __forceinline__ unsigned int pack_bf16(float lo, float hi) {
  union { float f; unsigned int u; } a, b;
  a.f = lo; b.f = hi;
  return __builtin_amdgcn_perm(b.u + 0x8000u, a.u + 0x8000u, 0x07060302u);
}

// ---------------- fp32 -> bf16 converts (single kernel) ----------------
// At the HBM achievable ceiling (~6.1 TB/s measured).
__global__ void cvt_all(const float* __restrict__ q,
                        const float* __restrict__ k,
                        const float* __restrict__ v,
                        const float* __restrict__ ipw,
                        const float* __restrict__ opw,
                        unsigned short* __restrict__ dst) {
  const size_t i = ((size_t)blockIdx.x * 256 + threadIdx.x) * 8;
  const float* src;
  float scale = 1.0f;
  if (i < 4194304) src = q + i;
  else if (i < 8388608) src = k + (i - 4194304);
  else if (i < 12582912) src = v + (i - 8388608);
  else {
    const size_t w = i - 12582912;
    if (w < 3145728) { src = ipw + w; if (w < 1048576) scale = QSCALE; }
    else src = opw + (w - 3145728);
  }
  float4 a = *(const float4*)src;
  float4 b = *(const float4*)(src + 4);
  uint4 o;
  o.x = cvt_bf16(a.x * scale) | ((unsigned int)cvt_bf16(a.y * scale) << 16);
  o.y = cvt_bf16(a.z * scale) | ((unsigned int)cvt_bf16(a.w * scale) << 16);
  o.z = cvt_bf16(b.x * scale) | ((unsigned int)cvt_bf16(b.y * scale) << 16);
  o.w = cvt_bf16(b.z * scale) | ((unsigned int)cvt_bf16(b.w * scale) << 16);
  *(uint4*)(dst + i) = o;
}

// ---------------- QKV projection GEMM ----------------
// R0-exact (best of 4 measured variants: 48.6 us): 128x128 tile, BK=64,
// single 32 KB LDS, two __syncthreads per K-step, 3 blocks/CU, XOR-swizzled
// LDS (swizzle folded into global src), XCD remap.
__global__ __launch_bounds__(256, 3) void gemm_qkv(
    const unsigned short* __restrict__ X,   // [3][4096][1024] bf16
    const unsigned short* __restrict__ W,   // [3072][1024] bf16 (wq pre-scaled)
    const float* __restrict__ bias,         // [3072] fp32
    unsigned short* __restrict__ Qh,        // [32][2048][64]
    unsigned short* __restrict__ Kh,        // [32][2048][64]
    unsigned short* __restrict__ Vt)        // [32][64][2048] key-permuted
{
  __shared__ unsigned short As[128 * 64];   // 16 KB
  __shared__ unsigned short Bs[128 * 64];   // 16 KB
  const int tid = threadIdx.x;
  const int wave = tid >> 6, lane = tid & 63;
  const int quad = lane >> 4, l16 = lane & 15;
  const int flat = blockIdx.x + (blockIdx.y << 3) + (blockIdx.z << 8);
  const int nf = (flat & 7) * 96 + (flat >> 3);
  const int z = nf >> 8;
  const int m0 = ((nf >> 3) & 31) * 128;
  const int n0 = (nf & 7) * 128;
  const unsigned short* Ab = X + (size_t)z * 4194304 + (size_t)m0 * 1024;
  const unsigned short* Bb = W + ((size_t)z * 1024 + n0) * 1024;
  const int wr = (wave >> 1) * 64, wc = (wave & 1) * 64;

  const f32x4 z4 = {0.f, 0.f, 0.f, 0.f};
  f32x4 acc[4][4];
#pragma unroll
  for (int i = 0; i < 4; ++i)
#pragma unroll
    for (int j = 0; j < 4; ++j) acc[i][j] = z4;

  for (int k0 = 0; k0 < 1024; k0 += 64) {
    __syncthreads();
#pragma unroll
    for (int j = 0; j < 4; ++j) {
      const int c = j * 256 + tid;          // chunk 0..1023
      const int row = c >> 3, pc = c & 7;   // 8x16B chunks per 64-elem row
      const int kc = pc ^ (row & 7);        // swizzle folded into global src
      gll16(Ab + (size_t)row * 1024 + k0 + kc * 8, &As[c * 8]);
      gll16(Bb + (size_t)row * 1024 + k0 + kc * 8, &Bs[c * 8]);
    }
    __syncthreads();
#pragma unroll
    for (int kk = 0; kk < 2; ++kk) {
      bf16x8 af[4], bfr[4];
#pragma unroll
      for (int rt = 0; rt < 4; ++rt) {
        const int row = wr + rt * 16 + l16;
        af[rt] = *(const bf16x8*)&As[row * 64 + ((kk * 4 + quad) ^ (row & 7)) * 8];
      }
#pragma unroll
      for (int ct = 0; ct < 4; ++ct) {
        const int row = wc + ct * 16 + l16;
        bfr[ct] = *(const bf16x8*)&Bs[row * 64 + ((kk * 4 + quad) ^ (row & 7)) * 8];
      }
#pragma unroll
      for (int rt = 0; rt < 4; ++rt)
#pragma unroll
        for (int ct = 0; ct < 4; ++ct)
          acc[rt][ct] = MFMA(af[rt], bfr[ct], acc[rt][ct]);
    }
  }

#pragma unroll
  for (int rt = 0; rt < 4; ++rt)
#pragma unroll
    for (int ct = 0; ct < 4; ++ct) {
      const int gn = n0 + wc + ct * 16 + l16;
      float bv = bias[z * 1024 + gn];
      if (z == 0) bv *= QSCALE;
      const int h = gn >> 6, d = gn & 63;
#pragma unroll
      for (int r = 0; r < 4; ++r) {
        const int gm = m0 + wr + rt * 16 + quad * 4 + r;  // m = t*2 + b
        const int t = gm >> 1, b = gm & 1;
        const int bh = b * 16 + h;
        const unsigned short o = cvt_bf16(acc[rt][ct][r] + bv);
        if (z == 0)      Qh[((size_t)bh * 2048 + t) * 64 + d] = o;
        else if (z == 1) Kh[((size_t)bh * 2048 + t) * 64 + d] = o;
        else {
          const int w32 = t & 31;   // pi: {16hi+4q+r} -> q*8 + hi*4 + r
          const int tp = (t & ~31) | (((w32 >> 2) & 3) << 3) | ((w32 >> 4) << 2) | (w32 & 3);
          Vt[((size_t)bh * 64 + d) * 2048 + tp] = o;
        }
      }
    }
}

// ---------------- flash attention ----------------
// R8 structure (QBLK=128, 512 blocks = 2/CU, W-B-I-C dbuf, setprio on PV).
// THIS ROUND: epilogue-only fix for the measured 262144 bank-conflict cycles:
//  - Fp pair-combine rows padded 64 -> 66 floats (4*66*4B % 128B = 32, so the
//    4 quad-groups land on distinct bank octets; was 4-way aliased).
//  - Ls duplicate store predicated on l16==0 (was 16 lanes to one address).
// Capacity: 2 pairs * 64 * 66 = 8448 floats <= KV's 16384. No sync change.
__global__ __launch_bounds__(256, 2) void attn(
    const unsigned short* __restrict__ Qh,
    const unsigned short* __restrict__ Kh,
    const unsigned short* __restrict__ Vt,
    unsigned short* __restrict__ O)   // [4096][1024] bf16 (row = t*2+b)
{
  __shared__ unsigned short KV[2][16384];  // 64 KB: per buf Ks [128][64] | Vs [64][128]
  __shared__ float Ls[128];                // pair-combine l partials
  const int tid = threadIdx.x;
  const int wave = tid >> 6, lane = tid & 63;
  const int quad = lane >> 4, l16 = lane & 15;
  const int pair = wave >> 1, kh = wave & 1;
  const int flat = blockIdx.x + (blockIdx.y << 4);   // grid (16,32)
  const int nf = (flat & 7) * 64 + (flat >> 3);      // XCD j: 4 whole bh's
  const int qt = nf & 15, bh = nf >> 4;
  const unsigned short* Qb = Qh + ((size_t)bh * 2048 + qt * 128 + pair * 64) * 64;
  const unsigned short* Kb = Kh + (size_t)bh * 2048 * 64;
  const unsigned short* Vb = Vt + (size_t)bh * 64 * 2048;

  bf16x8 qf[4][2];  // B-frags for S^T = K.Q^T; 4 q-groups of 16 rows
#pragma unroll
  for (int g = 0; g < 4; ++g)
#pragma unroll
    for (int kk = 0; kk < 2; ++kk)
      qf[g][kk] = *(const bf16x8*)(Qb + (size_t)(g * 16 + l16) * 64 + kk * 32 + quad * 8);

  const unsigned short* kp[4];
  const unsigned short* vp[4];
  int klo[4], vlo[4];
#pragma unroll
  for (int j = 0; j < 4; ++j) {
    const int c = wave * 256 + j * 64 + lane;   // chunk 0..1023
    const int r = c >> 3, cc = c & 7;
    kp[j] = Kb + (size_t)r * 64 + (cc ^ (r & 7)) * 8;
    klo[j] = c * 8;
    const int r2 = c >> 4, cc2 = c & 15;
    vp[j] = Vb + (size_t)r2 * 2048 + (cc2 ^ (r2 & 15)) * 8;
    vlo[j] = 8192 + c * 8;
  }

  pku ones;
  ones.u[0] = ones.u[1] = ones.u[2] = ones.u[3] = 0x3F803F80u;  // bf16 1.0 x8

  const f32x4 z4 = {0.f, 0.f, 0.f, 0.f};
  f32x4 oacc[4][4];
  f32x4 lacc[4] = {z4, z4, z4, z4};
#pragma unroll
  for (int g = 0; g < 4; ++g)
#pragma unroll
    for (int c = 0; c < 4; ++c) oacc[g][c] = z4;

#pragma unroll
  for (int j = 0; j < 4; ++j) {
    gll16(kp[j], &KV[0][klo[j]]);
    gll16(vp[j], &KV[0][vlo[j]]);
    kp[j] += 128 * 64;
    vp[j] += 128;
  }

#pragma unroll 1
  for (int it = 0; it < 16; ++it) {
    const int cur = it & 1;
    PIPE_SYNC();         // T(it) landed everywhere; buf[cur^1] free
    if (it < 15) {
#pragma unroll
      for (int j = 0; j < 4; ++j) {
        gll16(kp[j], &KV[cur ^ 1][klo[j]]);
        gll16(vp[j], &KV[cur ^ 1][vlo[j]]);
        kp[j] += 128 * 64;
        vp[j] += 128;
      }
    }
    const unsigned short* Ks = KV[cur];
    const unsigned short* Vs = KV[cur] + 8192;

#pragma unroll
    for (int jj = 0; jj < 2; ++jj) {
      unsigned int pk0[4][2], pk1[4][2];
#pragma unroll
      for (int half = 0; half < 2; ++half) {
        const int ct = jj * 2 + half;
        const int R = kh * 64 + ct * 16 + l16;
        bf16x8 kfr[2];
#pragma unroll
        for (int kk = 0; kk < 2; ++kk)
          kfr[kk] = *(const bf16x8*)&Ks[R * 64 + ((kk * 4 + quad) ^ (R & 7)) * 8];
#pragma unroll
        for (int g = 0; g < 4; ++g) {
          f32x4 sv = z4;
          sv = MFMA(kfr[0], qf[g][0], sv);
          sv = MFMA(kfr[1], qf[g][1], sv);
          f32x4 p;
#pragma unroll
          for (int r = 0; r < 4; ++r) p[r] = fast_exp2(sv[r]);
          pk0[g][half] = pack_bf16(p[0], p[1]);
          pk1[g][half] = pack_bf16(p[2], p[3]);
        }
      }
      const int jjg = kh * 2 + jj;
      __builtin_amdgcn_s_setprio(1);
#pragma unroll
      for (int ctd = 0; ctd < 4; ++ctd) {
        const int R = ctd * 16 + l16;
        const int phys = (jjg * 4 + quad) ^ (R & 15);
        const bf16x8 vv = *(const bf16x8*)&Vs[R * 128 + phys * 8];
#pragma unroll
        for (int g = 0; g < 4; ++g) {
          pku a;
          a.u[0] = pk0[g][0]; a.u[1] = pk1[g][0];
          a.u[2] = pk0[g][1]; a.u[3] = pk1[g][1];
          oacc[g][ctd] = MFMA(a.b, vv, oacc[g][ctd]);
        }
      }
#pragma unroll
      for (int g = 0; g < 4; ++g) {
        pku a;
        a.u[0] = pk0[g][0]; a.u[1] = pk1[g][0];
        a.u[2] = pk0[g][1]; a.u[3] = pk1[g][1];
        lacc[g] = MFMA(a.b, ones.b, lacc[g]);
      }
      __builtin_amdgcn_s_setprio(0);
    }
  }

  // pair-combine: Fp row stride 66 floats (bank-conflict-free across quads).
  __syncthreads();
  float* Fp = (float*)KV;               // pair region: pair*4224 floats [q][66]
  if (kh == 1) {
#pragma unroll
    for (int g = 0; g < 4; ++g) {
#pragma unroll
      for (int ctd = 0; ctd < 4; ++ctd)
#pragma unroll
        for (int r = 0; r < 4; ++r)
          Fp[pair * 4224 + (g * 16 + quad * 4 + r) * 66 + ctd * 16 + l16] = oacc[g][ctd][r];
      if (l16 == 0) {   // value uniform across l16; one lane stores
#pragma unroll
        for (int r = 0; r < 4; ++r)
          Ls[pair * 64 + g * 16 + quad * 4 + r] = lacc[g][r];
      }
    }
  }
  __syncthreads();
  if (kh == 0) {
    const int b = bh >> 4, h = bh & 15;
#pragma unroll
    for (int g = 0; g < 4; ++g)
#pragma unroll
      for (int r = 0; r < 4; ++r) {
        const int ql = g * 16 + quad * 4 + r;
        const float lv = lacc[g][r] + Ls[pair * 64 + ql];
        const float inv = 1.0f / lv;
        const int t = qt * 128 + pair * 64 + ql;
#pragma unroll
        for (int ctd = 0; ctd < 4; ++ctd) {
          const float val = oacc[g][ctd][r] + Fp[pair * 4224 + ql * 66 + ctd * 16 + l16];
          O[((size_t)t * 2 + b) * 1024 + h * 64 + ctd * 16 + l16] = cvt_bf16(val * inv);
        }
      }
  }
}

// ---------------- output projection GEMM ----------------
// R0-exact (best measured variant; 64x64 retile was -7 us): 128x64 tile,
// BK=64, single-buffer LDS, two __syncthreads per K-step, grid 512, XCD remap.
__global__ __launch_bounds__(256, 4) void gemm_out(
    const unsigned short* __restrict__ A,   // O: [4096][1024] bf16
    const unsigned short* __restrict__ W,   // Wo: [1024][1024] bf16
    const float* __restrict__ bias,         // [1024] fp32
    float* __restrict__ out)                // [4096][1024] fp32 = d_out
{
  __shared__ unsigned short As[128 * 64];   // 16 KB
  __shared__ unsigned short Bs[64 * 64];    // 8 KB
  const int tid = threadIdx.x;
  const int wave = tid >> 6, lane = tid & 63;
  const int quad = lane >> 4, l16 = lane & 15;
  const int flat = blockIdx.x + (blockIdx.y << 4);
  const int nf = (flat & 7) * 64 + (flat >> 3);
  const int m0 = (nf >> 4) * 128;
  const int n0 = (nf & 15) * 64;
  const unsigned short* Ab = A + (size_t)m0 * 1024;
  const unsigned short* Bb = W + (size_t)n0 * 1024;
  const int wr = (wave >> 1) * 64, wc = (wave & 1) * 32;

  const f32x4 z4 = {0.f, 0.f, 0.f, 0.f};
  f32x4 acc[4][2];
#pragma unroll
  for (int i = 0; i < 4; ++i)
#pragma unroll
    for (int j = 0; j < 2; ++j) acc[i][j] = z4;

  for (int k0 = 0; k0 < 1024; k0 += 64) {
    __syncthreads();
#pragma unroll
    for (int j = 0; j < 4; ++j) {          // A: 1024 chunks
      const int c = j * 256 + tid;
      const int row = c >> 3, pc = c & 7;
      const int kc = pc ^ (row & 7);
      gll16(Ab + (size_t)row * 1024 + k0 + kc * 8, &As[c * 8]);
    }
#pragma unroll
    for (int j = 0; j < 2; ++j) {          // B: 512 chunks
      const int c = j * 256 + tid;
      const int row = c >> 3, pc = c & 7;
      const int kc = pc ^ (row & 7);
      gll16(Bb + (size_t)row * 1024 + k0 + kc * 8, &Bs[c * 8]);
    }
    __syncthreads();
#pragma unroll
    for (int kk = 0; kk < 2; ++kk) {
      bf16x8 af[4], bfr[2];
#pragma unroll
      for (int rt = 0; rt < 4; ++rt) {
        const int row = wr + rt * 16 + l16;
        af[rt] = *(const bf16x8*)&As[row * 64 + ((kk * 4 + quad) ^ (row & 7)) * 8];
      }
#pragma unroll
      for (int ct = 0; ct < 2; ++ct) {
        const int row = wc + ct * 16 + l16;
        bfr[ct] = *(const bf16x8*)&Bs[row * 64 + ((kk * 4 + quad) ^ (row & 7)) * 8];
      }
#pragma unroll
      for (int rt = 0; rt < 4; ++rt)
#pragma unroll
        for (int ct = 0; ct < 2; ++ct)
          acc[rt][ct] = MFMA(af[rt], bfr[ct], acc[rt][ct]);
    }
  }

#pragma unroll
  for (int rt = 0; rt < 4; ++rt)
#pragma unroll
    for (int ct = 0; ct < 2; ++ct) {
      const int gn = n0 + wc + ct * 16 + l16;
      const float bv = bias[gn];
#pragma unroll
      for (int r = 0; r < 4; ++r) {
        const int gm = m0 + wr + rt * 16 + quad * 4 + r;
        out[(size_t)gm * 1024 + gn] = acc[rt][ct][r] + bv;
      }
    }
}

// ---------------- launch ----------------
extern "C" void kernel_launch(void* const* d_in, const int* in_sizes, int n_in,
                              void* d_out, int out_size, void* d_ws, size_t ws_size,
                              hipStream_t stream) {
  const float* q   = (const float*)d_in[0];
  const float* k   = (const float*)d_in[1];
  const float* v   = (const float*)d_in[2];
  const float* ipw = (const float*)d_in[3];
  const float* ipb = (const float*)d_in[4];
  const float* opw = (const float*)d_in[5];
  const float* opb = (const float*)d_in[6];

  unsigned short* ws = (unsigned short*)d_ws;
  unsigned short* X  = ws;              // 3 * 4096*1024      = 12582912
  unsigned short* Wb = ws + 12582912;   // 3072*1024          =  3145728
  unsigned short* Wo = ws + 15728640;   // 1024*1024          =  1048576
  unsigned short* Qh = ws + 16777216;   // 32*2048*64         =  4194304
  unsigned short* Kh = ws + 20971520;   //                       4194304
  unsigned short* Vx = ws + 25165824;   // V transposed+permuted 4194304
  unsigned short* Oa = ws + 29360128;   //                       4194304

  cvt_all<<<dim3(8192), 256, 0, stream>>>(q, k, v, ipw, opw, ws);
  gemm_qkv<<<dim3(8, 32, 3), 256, 0, stream>>>(X, Wb, ipb, Qh, Kh, Vx);
  attn<<<dim3(16, 32), 256, 0, stream>>>(Qh, Kh, Vx, Oa);
  gemm_out<<<dim3(16, 32), 256, 0, stream>>>(Oa, Wo, opb, (float*)d_out);
}